// Round 2
// baseline (548.155 us; speedup 1.0000x reference)
//
#include <hip/hip_runtime.h>
#include <math.h>

#define BB 16
#define TT 2048
#define DD 1024
#define THRESH 0.95f

// ---------------- Kernel 1: projection + sigmoid + mask ----------------
// alphas[b*T+t] = sigmoid(dot(hs[b,t,:], w) + bias) * hs_mask[b,t]
// One wave (64 lanes) per row; 4 waves / block.
__global__ __launch_bounds__(256) void proj_kernel(
    const float* __restrict__ hs, const float* __restrict__ hs_mask,
    const float* __restrict__ w, const float* __restrict__ bias,
    float* __restrict__ alphas)
{
    int row  = blockIdx.x * 4 + (threadIdx.x >> 6);   // b*T + t
    int lane = threadIdx.x & 63;
    const float4* hp = (const float4*)(hs + (size_t)row * DD);
    const float4* wp = (const float4*)w;
    float sum = 0.f;
#pragma unroll
    for (int j = 0; j < 4; ++j) {
        float4 h4 = hp[lane + 64 * j];
        float4 w4 = wp[lane + 64 * j];
        sum += h4.x * w4.x + h4.y * w4.y + h4.z * w4.z + h4.w * w4.w;
    }
#pragma unroll
    for (int off = 32; off; off >>= 1) sum += __shfl_down(sum, off, 64);
    if (lane == 0) {
        float x  = sum + bias[0];
        float al = 1.f / (1.f + expf(-x));   // expf: <1ulp; fire decisions are rounding-sensitive
        alphas[row] = al * hs_mask[row];
    }
}

// ---------------- Kernel 2: scalar integrate-and-fire scan ----------------
// One block per batch. Whole block: stage alphas to LDS + parallel double-sum
// for len_labels. Thread 0: serial fp32 chain (bit-matches reference order),
// chunked by 16 with register double-buffering so ds_read latency (~120cy)
// hides under the ~192cy dependent-VALU chain of the previous chunk.
__global__ __launch_bounds__(256) void scan_kernel(
    const float* __restrict__ alphas, float* __restrict__ cur,
    int* __restrict__ fire_times, int* __restrict__ n_fires,
    int* __restrict__ len_labels)
{
    __shared__ float sa[TT];
    __shared__ double red[4];
    int b = blockIdx.x;
    const float* ap = alphas + (size_t)b * TT;
    double dsum = 0.0;
    for (int t = threadIdx.x; t < TT; t += 256) {
        float a = ap[t];
        sa[t] = a;
        dsum += (double)a;
    }
#pragma unroll
    for (int off = 32; off; off >>= 1) dsum += __shfl_down(dsum, off, 64);
    if ((threadIdx.x & 63) == 0) red[threadIdx.x >> 6] = dsum;
    __syncthreads();

    if (threadIdx.x == 0) {
        double tot = red[0] + red[1] + red[2] + red[3];
        len_labels[b] = (int)__double2int_rn(tot);

        float integ = 0.f;
        int nf = 0;
        float* cp = cur + (size_t)b * TT;
        int*   fp = fire_times + (size_t)b * TT;
        const float4* s4 = (const float4*)sa;

        float4 bufA[4], bufB[4];
#pragma unroll
        for (int j = 0; j < 4; ++j) bufA[j] = s4[j];

        for (int chunk = 0; chunk < TT / 16; ++chunk) {
            float4* curb = (chunk & 1) ? bufB : bufA;
            float4* nxtb = (chunk & 1) ? bufA : bufB;
            if (chunk + 1 < TT / 16) {
#pragma unroll
                for (int j = 0; j < 4; ++j) nxtb[j] = s4[(chunk + 1) * 4 + j];
            }
            float4 co[4];
            int tbase = chunk * 16;
#pragma unroll
            for (int j = 0; j < 16; ++j) {
                float a    = ((const float*)curb)[j];
                float dist = 1.f - integ;         // off critical chain
                integ += a;                       // chain: add
                bool fire = integ > THRESH;       // chain: cmp
                ((float*)co)[j] = fire ? dist : a;
                if (fire) { integ -= 1.f; fp[nf++] = tbase + j; }  // chain: cndmask (sub exact)
            }
            float4* cp4 = (float4*)(cp + tbase);
#pragma unroll
            for (int j = 0; j < 4; ++j) cp4[j] = co[j];
        }
        n_fires[b] = nf;
    }
}

// ---------------- Kernel 3: gather segments into packed output + mask ----------------
// Block ro = b*T + r handles output row r of batch b (D=1024 floats, 256 thr x float4).
// Row r (< n_fires): leftover of previous fire + sum of cur_t * h_t through t_end.
// Row r (>= n_fires): zeros (d_out is poisoned).
__global__ __launch_bounds__(256) void gather_kernel(
    const float* __restrict__ hs, const float* __restrict__ alphas,
    const float* __restrict__ cur, const int* __restrict__ fire_times,
    const int* __restrict__ n_fires, const int* __restrict__ len_labels,
    float* __restrict__ out, float* __restrict__ out_mask)
{
    int ro = blockIdx.x;           // b*T + r
    int b  = ro >> 11;             // / TT
    int r  = ro & (TT - 1);
    if (threadIdx.x == 0)
        out_mask[ro] = (r < len_labels[b]) ? 1.f : 0.f;

    float4* op = (float4*)(out + (size_t)ro * DD);
    int ti = threadIdx.x;
    if (r >= n_fires[b]) {
        float4 z = {0.f, 0.f, 0.f, 0.f};
        op[ti] = z;
        return;
    }
    int t_end  = fire_times[b * TT + r];
    int t_prev = r ? fire_times[b * TT + r - 1] : -1;

    const float4* hsb = (const float4*)(hs + (size_t)b * TT * DD);
    float4 acc = {0.f, 0.f, 0.f, 0.f};
    if (t_prev >= 0) {
        // leftover from the previous fire: (alpha - cur) * h_{t_prev}
        float c = alphas[b * TT + t_prev] - cur[b * TT + t_prev];
        float4 h = hsb[(size_t)t_prev * 256 + ti];
        acc.x += c * h.x; acc.y += c * h.y; acc.z += c * h.z; acc.w += c * h.w;
    }
    for (int t = t_prev + 1; t <= t_end; ++t) {
        float c = cur[b * TT + t];     // broadcast load
        float4 h = hsb[(size_t)t * 256 + ti];
        acc.x += c * h.x; acc.y += c * h.y; acc.z += c * h.z; acc.w += c * h.w;
    }
    op[ti] = acc;
}

extern "C" void kernel_launch(void* const* d_in, const int* in_sizes, int n_in,
                              void* d_out, int out_size, void* d_ws, size_t ws_size,
                              hipStream_t stream) {
    const float* hs      = (const float*)d_in[0];   // [B,T,D]
    const float* hs_mask = (const float*)d_in[1];   // [B,1,T]
    const float* w       = (const float*)d_in[2];   // [D]
    const float* bias    = (const float*)d_in[3];   // scalar

    float* out      = (float*)d_out;                       // [B,T,D]
    float* out_mask = out + (size_t)BB * TT * DD;          // [B,1,T] as 0/1 floats

    float* alphas     = (float*)d_ws;                      // B*T floats
    float* cur        = alphas + BB * TT;                  // B*T floats
    int*   fire_times = (int*)(cur + BB * TT);             // B*T ints
    int*   n_fires    = fire_times + BB * TT;              // B ints
    int*   len_labels = n_fires + BB;                      // B ints

    proj_kernel<<<BB * TT / 4, 256, 0, stream>>>(hs, hs_mask, w, bias, alphas);
    scan_kernel<<<BB, 256, 0, stream>>>(alphas, cur, fire_times, n_fires, len_labels);
    gather_kernel<<<BB * TT, 256, 0, stream>>>(hs, alphas, cur, fire_times,
                                               n_fires, len_labels, out, out_mask);
}

// Round 3
// 346.950 us; speedup vs baseline: 1.5799x; 1.5799x over previous
//
#include <hip/hip_runtime.h>
#include <math.h>

#define BB 16
#define TT 2048
#define DD 1024
#define THRESH 0.95f

// ---------------- Kernel 1: projection + sigmoid + mask ----------------
// alphas[b*T+t] = sigmoid(dot(hs[b,t,:], w) + bias) * hs_mask[b,t]
// One wave (64 lanes) per row; 4 waves / block.
__global__ __launch_bounds__(256) void proj_kernel(
    const float* __restrict__ hs, const float* __restrict__ hs_mask,
    const float* __restrict__ w, const float* __restrict__ bias,
    float* __restrict__ alphas)
{
    int row  = blockIdx.x * 4 + (threadIdx.x >> 6);   // b*T + t
    int lane = threadIdx.x & 63;
    const float4* hp = (const float4*)(hs + (size_t)row * DD);
    const float4* wp = (const float4*)w;
    float sum = 0.f;
#pragma unroll
    for (int j = 0; j < 4; ++j) {
        float4 h4 = hp[lane + 64 * j];
        float4 w4 = wp[lane + 64 * j];
        sum += h4.x * w4.x + h4.y * w4.y + h4.z * w4.z + h4.w * w4.w;
    }
#pragma unroll
    for (int off = 32; off; off >>= 1) sum += __shfl_down(sum, off, 64);
    if (lane == 0) {
        float x  = sum + bias[0];
        float al = 1.f / (1.f + expf(-x));   // expf: <1ulp; fire decisions are rounding-sensitive
        alphas[row] = al * hs_mask[row];
    }
}

// ---------------- Kernel 2: scalar integrate-and-fire scan ----------------
// One block per batch. Whole block: stage alphas to LDS + parallel double-sum
// for len_labels. Thread 0: serial fp32 chain (bit-matches reference op order).
// 16-step chunks, LDS loaded as 4 NAMED float4s (constant indices — SROA-safe;
// R2's pointer-selected double-buffer spilled to scratch and regressed 2x).
// Branchless fire recording: unconditional store + conditional increment.
__global__ __launch_bounds__(256) void scan_kernel(
    const float* __restrict__ alphas, float* __restrict__ cur,
    int* __restrict__ fire_times, int* __restrict__ n_fires,
    int* __restrict__ len_labels)
{
    __shared__ float sa[TT];
    __shared__ double red[4];
    int b = blockIdx.x;
    const float* ap = alphas + (size_t)b * TT;
    double dsum = 0.0;
    for (int t = threadIdx.x; t < TT; t += 256) {
        float a = ap[t];
        sa[t] = a;
        dsum += (double)a;
    }
#pragma unroll
    for (int off = 32; off; off >>= 1) dsum += __shfl_down(dsum, off, 64);
    if ((threadIdx.x & 63) == 0) red[threadIdx.x >> 6] = dsum;
    __syncthreads();

    if (threadIdx.x == 0) {
        double tot = red[0] + red[1] + red[2] + red[3];
        len_labels[b] = (int)__double2int_rn(tot);

        float integ = 0.f;
        int nf = 0;
        float* cp = cur + (size_t)b * TT;
        int*   fp = fire_times + (size_t)b * TT;
        const float4* s4 = (const float4*)sa;

        for (int chunk = 0; chunk < TT / 16; ++chunk) {
            int tbase = chunk * 16;
            // 4 independent ds_read_b128 into named vars — one waitcnt, then
            // a pure-VALU 16-step chain (~192 cyc) that amortizes the latency.
            float4 v0 = s4[chunk * 4 + 0];
            float4 v1 = s4[chunk * 4 + 1];
            float4 v2 = s4[chunk * 4 + 2];
            float4 v3 = s4[chunk * 4 + 3];
            float av[16] = {v0.x, v0.y, v0.z, v0.w,
                            v1.x, v1.y, v1.z, v1.w,
                            v2.x, v2.y, v2.z, v2.w,
                            v3.x, v3.y, v3.z, v3.w};
            float cv[16];
#pragma unroll
            for (int j = 0; j < 16; ++j) {
                float a    = av[j];
                float dist = 1.f - integ;            // off critical chain
                integ += a;                          // chain: v_add
                bool fire = integ > THRESH;          // chain: v_cmp
                cv[j] = fire ? dist : a;
                fp[nf] = tbase + j;                  // unconditional; dead if !fire
                nf += fire ? 1 : 0;
                integ = fire ? integ - 1.f : integ;  // chain: v_cndmask (sub exact)
            }
            float4* cp4 = (float4*)(cp + tbase);
            cp4[0] = {cv[0],  cv[1],  cv[2],  cv[3]};
            cp4[1] = {cv[4],  cv[5],  cv[6],  cv[7]};
            cp4[2] = {cv[8],  cv[9],  cv[10], cv[11]};
            cp4[3] = {cv[12], cv[13], cv[14], cv[15]};
        }
        n_fires[b] = nf;
    }
}

// ---------------- Kernel 3: gather segments into packed output + mask ----------------
// Block ro = b*T + r handles output row r of batch b (D=1024 floats, 256 thr x float4).
// Row r (< n_fires): leftover of previous fire + sum of cur_t * h_t through t_end.
// Row r (>= n_fires): zeros (d_out is poisoned).
__global__ __launch_bounds__(256) void gather_kernel(
    const float* __restrict__ hs, const float* __restrict__ alphas,
    const float* __restrict__ cur, const int* __restrict__ fire_times,
    const int* __restrict__ n_fires, const int* __restrict__ len_labels,
    float* __restrict__ out, float* __restrict__ out_mask)
{
    int ro = blockIdx.x;           // b*T + r
    int b  = ro >> 11;             // / TT
    int r  = ro & (TT - 1);
    if (threadIdx.x == 0)
        out_mask[ro] = (r < len_labels[b]) ? 1.f : 0.f;

    float4* op = (float4*)(out + (size_t)ro * DD);
    int ti = threadIdx.x;
    if (r >= n_fires[b]) {
        float4 z = {0.f, 0.f, 0.f, 0.f};
        op[ti] = z;
        return;
    }
    int t_end  = fire_times[b * TT + r];
    int t_prev = r ? fire_times[b * TT + r - 1] : -1;

    const float4* hsb = (const float4*)(hs + (size_t)b * TT * DD);
    float4 acc = {0.f, 0.f, 0.f, 0.f};
    if (t_prev >= 0) {
        // leftover from the previous fire: (alpha - cur) * h_{t_prev}
        float c = alphas[b * TT + t_prev] - cur[b * TT + t_prev];
        float4 h = hsb[(size_t)t_prev * 256 + ti];
        acc.x += c * h.x; acc.y += c * h.y; acc.z += c * h.z; acc.w += c * h.w;
    }
    for (int t = t_prev + 1; t <= t_end; ++t) {
        float c = cur[b * TT + t];     // broadcast load
        float4 h = hsb[(size_t)t * 256 + ti];
        acc.x += c * h.x; acc.y += c * h.y; acc.z += c * h.z; acc.w += c * h.w;
    }
    op[ti] = acc;
}

extern "C" void kernel_launch(void* const* d_in, const int* in_sizes, int n_in,
                              void* d_out, int out_size, void* d_ws, size_t ws_size,
                              hipStream_t stream) {
    const float* hs      = (const float*)d_in[0];   // [B,T,D]
    const float* hs_mask = (const float*)d_in[1];   // [B,1,T]
    const float* w       = (const float*)d_in[2];   // [D]
    const float* bias    = (const float*)d_in[3];   // scalar

    float* out      = (float*)d_out;                       // [B,T,D]
    float* out_mask = out + (size_t)BB * TT * DD;          // [B,1,T] as 0/1 floats

    float* alphas     = (float*)d_ws;                      // B*T floats
    float* cur        = alphas + BB * TT;                  // B*T floats
    int*   fire_times = (int*)(cur + BB * TT);             // B*T ints
    int*   n_fires    = fire_times + BB * TT;              // B ints
    int*   len_labels = n_fires + BB;                      // B ints

    proj_kernel<<<BB * TT / 4, 256, 0, stream>>>(hs, hs_mask, w, bias, alphas);
    scan_kernel<<<BB, 256, 0, stream>>>(alphas, cur, fire_times, n_fires, len_labels);
    gather_kernel<<<BB * TT, 256, 0, stream>>>(hs, alphas, cur, fire_times,
                                               n_fires, len_labels, out, out_mask);
}

// Round 4
// 342.099 us; speedup vs baseline: 1.6023x; 1.0142x over previous
//
#include <hip/hip_runtime.h>
#include <math.h>

#define BB 16
#define TT 2048
#define DD 1024
#define THRESH 0.95f

// ---------------- Kernel 1: projection + sigmoid + mask ----------------
// alphas[b*T+t] = sigmoid(dot(hs[b,t,:], w) + bias) * hs_mask[b,t]
// One wave (64 lanes) per row; 4 waves / block.
__global__ __launch_bounds__(256) void proj_kernel(
    const float* __restrict__ hs, const float* __restrict__ hs_mask,
    const float* __restrict__ w, const float* __restrict__ bias,
    float* __restrict__ alphas)
{
    int row  = blockIdx.x * 4 + (threadIdx.x >> 6);   // b*T + t
    int lane = threadIdx.x & 63;
    const float4* hp = (const float4*)(hs + (size_t)row * DD);
    const float4* wp = (const float4*)w;
    float sum = 0.f;
#pragma unroll
    for (int j = 0; j < 4; ++j) {
        float4 h4 = hp[lane + 64 * j];
        float4 w4 = wp[lane + 64 * j];
        sum += h4.x * w4.x + h4.y * w4.y + h4.z * w4.z + h4.w * w4.w;
    }
#pragma unroll
    for (int off = 32; off; off >>= 1) sum += __shfl_down(sum, off, 64);
    if (lane == 0) {
        float x  = sum + bias[0];
        float al = 1.f / (1.f + expf(-x));   // expf: <1ulp; fire decisions are rounding-sensitive
        alphas[row] = al * hs_mask[row];
    }
}

// ---------------- Kernel 2: scalar integrate-and-fire scan ----------------
// One block per batch. Block: stage alphas to LDS + parallel double-sum for
// len_labels. Thread 0: serial fp32 chain (bit-matches reference op order),
// 16-step unrolled chunks. ALL serial-loop outputs go to LDS (ds_write drains
// in tens of cycles) — R3 showed per-chunk global stores force a vmcnt drain
// on register reuse (~1780 cyc/chunk). Block copies LDS->global at the end.
__global__ __launch_bounds__(256) void scan_kernel(
    const float* __restrict__ alphas, float* __restrict__ cur,
    int* __restrict__ fire_times, int* __restrict__ n_fires,
    int* __restrict__ len_labels)
{
    __shared__ float  sa[TT];   // alphas in
    __shared__ float  sc[TT];   // cur out
    __shared__ int    sf[TT];   // fire_times out
    __shared__ double red[4];
    int b = blockIdx.x;
    const float* ap = alphas + (size_t)b * TT;
    double dsum = 0.0;
    for (int t = threadIdx.x; t < TT; t += 256) {
        float a = ap[t];
        sa[t] = a;
        dsum += (double)a;
    }
#pragma unroll
    for (int off = 32; off; off >>= 1) dsum += __shfl_down(dsum, off, 64);
    if ((threadIdx.x & 63) == 0) red[threadIdx.x >> 6] = dsum;
    __syncthreads();

    if (threadIdx.x == 0) {
        double tot = red[0] + red[1] + red[2] + red[3];
        len_labels[b] = (int)__double2int_rn(tot);

        float integ = 0.f;
        int nf = 0;
        const float4* s4 = (const float4*)sa;
        float4* c4 = (float4*)sc;

        for (int chunk = 0; chunk < TT / 16; ++chunk) {
            int tbase = chunk * 16;
            // 4 independent ds_read_b128 (named vars, constant idx — SROA-safe).
            float4 v0 = s4[chunk * 4 + 0];
            float4 v1 = s4[chunk * 4 + 1];
            float4 v2 = s4[chunk * 4 + 2];
            float4 v3 = s4[chunk * 4 + 3];
            float av[16] = {v0.x, v0.y, v0.z, v0.w,
                            v1.x, v1.y, v1.z, v1.w,
                            v2.x, v2.y, v2.z, v2.w,
                            v3.x, v3.y, v3.z, v3.w};
            float cv[16];
#pragma unroll
            for (int j = 0; j < 16; ++j) {
                float a    = av[j];
                float dist = 1.f - integ;            // off critical chain
                integ += a;                          // chain: v_add
                bool fire = integ > THRESH;          // chain: v_cmp
                cv[j] = fire ? dist : a;
                sf[nf] = tbase + j;                  // LDS store; dead if !fire
                nf += fire ? 1 : 0;
                integ = fire ? integ - 1.f : integ;  // chain: v_cndmask (sub exact)
            }
            c4[chunk * 4 + 0] = {cv[0],  cv[1],  cv[2],  cv[3]};
            c4[chunk * 4 + 1] = {cv[4],  cv[5],  cv[6],  cv[7]};
            c4[chunk * 4 + 2] = {cv[8],  cv[9],  cv[10], cv[11]};
            c4[chunk * 4 + 3] = {cv[12], cv[13], cv[14], cv[15]};
        }
        n_fires[b] = nf;
    }
    __syncthreads();

    // Parallel coalesced copy-out: cur (float4) and fire_times (int4).
    // Slots past n_fires are uninit-LDS garbage but never read by gather.
    float4* cg = (float4*)(cur + (size_t)b * TT);
    int4*   fg = (int4*)(fire_times + (size_t)b * TT);
    const float4* cl = (const float4*)sc;
    const int4*   fl = (const int4*)sf;
    for (int i = threadIdx.x; i < TT / 4; i += 256) {
        cg[i] = cl[i];
        fg[i] = fl[i];
    }
}

// ---------------- Kernel 3: gather segments into packed output + mask ----------------
// Block ro = b*T + r handles output row r of batch b (D=1024 floats, 256 thr x float4).
// Row r (< n_fires): leftover of previous fire + sum of cur_t * h_t through t_end.
// Row r (>= n_fires): zeros (d_out is poisoned).
__global__ __launch_bounds__(256) void gather_kernel(
    const float* __restrict__ hs, const float* __restrict__ alphas,
    const float* __restrict__ cur, const int* __restrict__ fire_times,
    const int* __restrict__ n_fires, const int* __restrict__ len_labels,
    float* __restrict__ out, float* __restrict__ out_mask)
{
    int ro = blockIdx.x;           // b*T + r
    int b  = ro >> 11;             // / TT
    int r  = ro & (TT - 1);
    if (threadIdx.x == 0)
        out_mask[ro] = (r < len_labels[b]) ? 1.f : 0.f;

    float4* op = (float4*)(out + (size_t)ro * DD);
    int ti = threadIdx.x;
    if (r >= n_fires[b]) {
        float4 z = {0.f, 0.f, 0.f, 0.f};
        op[ti] = z;
        return;
    }
    int t_end  = fire_times[b * TT + r];
    int t_prev = r ? fire_times[b * TT + r - 1] : -1;

    const float4* hsb = (const float4*)(hs + (size_t)b * TT * DD);
    float4 acc = {0.f, 0.f, 0.f, 0.f};
    if (t_prev >= 0) {
        // leftover from the previous fire: (alpha - cur) * h_{t_prev}
        float c = alphas[b * TT + t_prev] - cur[b * TT + t_prev];
        float4 h = hsb[(size_t)t_prev * 256 + ti];
        acc.x += c * h.x; acc.y += c * h.y; acc.z += c * h.z; acc.w += c * h.w;
    }
    for (int t = t_prev + 1; t <= t_end; ++t) {
        float c = cur[b * TT + t];     // broadcast load
        float4 h = hsb[(size_t)t * 256 + ti];
        acc.x += c * h.x; acc.y += c * h.y; acc.z += c * h.z; acc.w += c * h.w;
    }
    op[ti] = acc;
}

extern "C" void kernel_launch(void* const* d_in, const int* in_sizes, int n_in,
                              void* d_out, int out_size, void* d_ws, size_t ws_size,
                              hipStream_t stream) {
    const float* hs      = (const float*)d_in[0];   // [B,T,D]
    const float* hs_mask = (const float*)d_in[1];   // [B,1,T]
    const float* w       = (const float*)d_in[2];   // [D]
    const float* bias    = (const float*)d_in[3];   // scalar

    float* out      = (float*)d_out;                       // [B,T,D]
    float* out_mask = out + (size_t)BB * TT * DD;          // [B,1,T] as 0/1 floats

    float* alphas     = (float*)d_ws;                      // B*T floats
    float* cur        = alphas + BB * TT;                  // B*T floats
    int*   fire_times = (int*)(cur + BB * TT);             // B*T ints
    int*   n_fires    = fire_times + BB * TT;              // B ints
    int*   len_labels = n_fires + BB;                      // B ints

    proj_kernel<<<BB * TT / 4, 256, 0, stream>>>(hs, hs_mask, w, bias, alphas);
    scan_kernel<<<BB, 256, 0, stream>>>(alphas, cur, fire_times, n_fires, len_labels);
    gather_kernel<<<BB * TT, 256, 0, stream>>>(hs, alphas, cur, fire_times,
                                               n_fires, len_labels, out, out_mask);
}

// Round 5
// 322.705 us; speedup vs baseline: 1.6986x; 1.0601x over previous
//
#include <hip/hip_runtime.h>
#include <math.h>

#define BB 16
#define TT 2048
#define DD 1024
#define THRESH 0.95f

// ---------------- Kernel 1: projection + sigmoid + mask ----------------
__global__ __launch_bounds__(256) void proj_kernel(
    const float* __restrict__ hs, const float* __restrict__ hs_mask,
    const float* __restrict__ w, const float* __restrict__ bias,
    float* __restrict__ alphas)
{
    int row  = blockIdx.x * 4 + (threadIdx.x >> 6);   // b*T + t
    int lane = threadIdx.x & 63;
    const float4* hp = (const float4*)(hs + (size_t)row * DD);
    const float4* wp = (const float4*)w;
    float sum = 0.f;
#pragma unroll
    for (int j = 0; j < 4; ++j) {
        float4 h4 = hp[lane + 64 * j];
        float4 w4 = wp[lane + 64 * j];
        sum += h4.x * w4.x + h4.y * w4.y + h4.z * w4.z + h4.w * w4.w;
    }
#pragma unroll
    for (int off = 32; off; off >>= 1) sum += __shfl_down(sum, off, 64);
    if (lane == 0) {
        float x  = sum + bias[0];
        float al = 1.f / (1.f + expf(-x));   // expf: fire decisions are rounding-sensitive
        alphas[row] = al * hs_mask[row];
    }
}

// ---------------- Kernel 2: integrate-and-fire scan ----------------
// Serial fp32 chain on thread 0 (bit-matches reference op order) with ZERO
// local arrays / dynamic-index stores (R3/R4: allocas -> scratch, ~108cy/step).
// Fires recorded as a 32-bit mask per 32-step chunk; wave 0 expands masks to
// fire_times via popcount + shfl prefix scan afterwards.

// One scan step. A = alpha_t. Chain: v_add -> v_cmp -> v_cndmask (~12cy).
#define STEP(A, CREF, BIT)                       \
    {                                            \
        float pre  = integ + (A);                \
        bool  fire = pre > THRESH;               \
        (CREF) = fire ? (1.f - integ) : (A);     \
        m |= fire ? (1u << (BIT)) : 0u;          \
        integ = fire ? (pre - 1.f) : pre;        \
    }
// 4 steps on one named float4; result quad stored to LDS immediately.
#define GRP(V, IDX, B)                           \
    {                                            \
        float4 cc;                               \
        STEP((V).x, cc.x, (B) + 0)               \
        STEP((V).y, cc.y, (B) + 1)               \
        STEP((V).z, cc.z, (B) + 2)               \
        STEP((V).w, cc.w, (B) + 3)               \
        c4[ch * 8 + (IDX)] = cc;                 \
    }

__global__ __launch_bounds__(256) void scan_kernel(
    const float* __restrict__ alphas, float* __restrict__ cur,
    int* __restrict__ fire_times, int* __restrict__ n_fires,
    int* __restrict__ len_labels)
{
    __shared__ float    sa[TT];        // alphas in
    __shared__ float    sc[TT];        // cur out
    __shared__ int      sf[TT];        // fire_times out
    __shared__ unsigned smask[TT/32];  // fire bitmask per 32-step chunk
    __shared__ double   red[4];
    int b = blockIdx.x;
    const float* ap = alphas + (size_t)b * TT;
    double dsum = 0.0;
    for (int t = threadIdx.x; t < TT; t += 256) {
        float a = ap[t];
        sa[t] = a;
        dsum += (double)a;
    }
#pragma unroll
    for (int off = 32; off; off >>= 1) dsum += __shfl_down(dsum, off, 64);
    if ((threadIdx.x & 63) == 0) red[threadIdx.x >> 6] = dsum;
    __syncthreads();

    if (threadIdx.x == 0) {
        len_labels[b] = (int)__double2int_rn(red[0] + red[1] + red[2] + red[3]);

        float integ = 0.f;
        const float4* s4 = (const float4*)sa;
        float4*       c4 = (float4*)sc;
        for (int ch = 0; ch < TT / 32; ++ch) {
            // 8 named ds_read_b128; later quads' waits overlap earlier compute.
            float4 v0 = s4[ch * 8 + 0];
            float4 v1 = s4[ch * 8 + 1];
            float4 v2 = s4[ch * 8 + 2];
            float4 v3 = s4[ch * 8 + 3];
            float4 v4 = s4[ch * 8 + 4];
            float4 v5 = s4[ch * 8 + 5];
            float4 v6 = s4[ch * 8 + 6];
            float4 v7 = s4[ch * 8 + 7];
            unsigned m = 0;
            GRP(v0, 0,  0) GRP(v1, 1,  4) GRP(v2, 2,  8) GRP(v3, 3, 12)
            GRP(v4, 4, 16) GRP(v5, 5, 20) GRP(v6, 6, 24) GRP(v7, 7, 28)
            smask[ch] = m;
        }
    }
    __syncthreads();

    // Wave 0: expand chunk masks -> fire times (order-preserving).
    if (threadIdx.x < 64) {
        unsigned m = smask[threadIdx.x];
        int cnt  = __popc(m);
        int pref = cnt;                       // inclusive prefix over 64 chunks
#pragma unroll
        for (int off = 1; off < 64; off <<= 1) {
            int y = __shfl_up(pref, off, 64);
            if ((int)threadIdx.x >= off) pref += y;
        }
        int pos    = pref - cnt;              // exclusive
        int base_t = threadIdx.x * 32;
        while (m) {
            int j = __ffs(m) - 1;
            sf[pos++] = base_t + j;
            m &= m - 1;
        }
        if (threadIdx.x == 63) n_fires[b] = pref;
    }
    __syncthreads();

    // Coalesced copy-out (slots past n_fires are garbage but never read).
    float4* cg = (float4*)(cur + (size_t)b * TT);
    int4*   fg = (int4*)(fire_times + (size_t)b * TT);
    const float4* cl = (const float4*)sc;
    const int4*   fl = (const int4*)sf;
    for (int i = threadIdx.x; i < TT / 4; i += 256) {
        cg[i] = cl[i];
        fg[i] = fl[i];
    }
}

// ---------------- Kernel 3: gather segments into packed output + mask ----------------
__global__ __launch_bounds__(256) void gather_kernel(
    const float* __restrict__ hs, const float* __restrict__ alphas,
    const float* __restrict__ cur, const int* __restrict__ fire_times,
    const int* __restrict__ n_fires, const int* __restrict__ len_labels,
    float* __restrict__ out, float* __restrict__ out_mask)
{
    int ro = blockIdx.x;           // b*T + r
    int b  = ro >> 11;             // / TT
    int r  = ro & (TT - 1);
    if (threadIdx.x == 0)
        out_mask[ro] = (r < len_labels[b]) ? 1.f : 0.f;

    float4* op = (float4*)(out + (size_t)ro * DD);
    int ti = threadIdx.x;
    if (r >= n_fires[b]) {
        float4 z = {0.f, 0.f, 0.f, 0.f};
        op[ti] = z;
        return;
    }
    int t_end  = fire_times[b * TT + r];
    int t_prev = r ? fire_times[b * TT + r - 1] : -1;

    const float4* hsb = (const float4*)(hs + (size_t)b * TT * DD);
    float4 acc = {0.f, 0.f, 0.f, 0.f};
    if (t_prev >= 0) {
        float c = alphas[b * TT + t_prev] - cur[b * TT + t_prev];
        float4 h = hsb[(size_t)t_prev * 256 + ti];
        acc.x += c * h.x; acc.y += c * h.y; acc.z += c * h.z; acc.w += c * h.w;
    }
    for (int t = t_prev + 1; t <= t_end; ++t) {
        float c = cur[b * TT + t];     // broadcast load
        float4 h = hsb[(size_t)t * 256 + ti];
        acc.x += c * h.x; acc.y += c * h.y; acc.z += c * h.z; acc.w += c * h.w;
    }
    op[ti] = acc;
}

extern "C" void kernel_launch(void* const* d_in, const int* in_sizes, int n_in,
                              void* d_out, int out_size, void* d_ws, size_t ws_size,
                              hipStream_t stream) {
    const float* hs      = (const float*)d_in[0];   // [B,T,D]
    const float* hs_mask = (const float*)d_in[1];   // [B,1,T]
    const float* w       = (const float*)d_in[2];   // [D]
    const float* bias    = (const float*)d_in[3];   // scalar

    float* out      = (float*)d_out;                       // [B,T,D]
    float* out_mask = out + (size_t)BB * TT * DD;          // [B,1,T] as 0/1 floats

    float* alphas     = (float*)d_ws;                      // B*T floats
    float* cur        = alphas + BB * TT;                  // B*T floats
    int*   fire_times = (int*)(cur + BB * TT);             // B*T ints
    int*   n_fires    = fire_times + BB * TT;              // B ints
    int*   len_labels = n_fires + BB;                      // B ints

    proj_kernel<<<BB * TT / 4, 256, 0, stream>>>(hs, hs_mask, w, bias, alphas);
    scan_kernel<<<BB, 256, 0, stream>>>(alphas, cur, fire_times, n_fires, len_labels);
    gather_kernel<<<BB * TT, 256, 0, stream>>>(hs, alphas, cur, fire_times,
                                               n_fires, len_labels, out, out_mask);
}

// Round 7
// 309.533 us; speedup vs baseline: 1.7709x; 1.0426x over previous
//
#include <hip/hip_runtime.h>
#include <math.h>

#define BB 16
#define TT 2048
#define DD 1024
#define THRESH 0.95f

// ---------------- Kernel 1: projection + sigmoid + mask ----------------
__global__ __launch_bounds__(256) void proj_kernel(
    const float* __restrict__ hs, const float* __restrict__ hs_mask,
    const float* __restrict__ w, const float* __restrict__ bias,
    float* __restrict__ alphas)
{
    int row  = blockIdx.x * 4 + (threadIdx.x >> 6);   // b*T + t
    int lane = threadIdx.x & 63;
    const float4* hp = (const float4*)(hs + (size_t)row * DD);
    const float4* wp = (const float4*)w;
    float sum = 0.f;
#pragma unroll
    for (int j = 0; j < 4; ++j) {
        float4 h4 = hp[lane + 64 * j];
        float4 w4 = wp[lane + 64 * j];
        sum += h4.x * w4.x + h4.y * w4.y + h4.z * w4.z + h4.w * w4.w;
    }
#pragma unroll
    for (int off = 32; off; off >>= 1) sum += __shfl_down(sum, off, 64);
    if (lane == 0) {
        float x  = sum + bias[0];
        float al = 1.f / (1.f + expf(-x));   // expf: fire decisions are rounding-sensitive
        alphas[row] = al * hs_mask[row];
    }
}

// ---------------- Kernel 2: integrate-and-fire scan, register-file version ----------------
// One wave per batch. 8 named VGPRs x 64 lanes hold 512 alphas per outer pass.
// The serial fp32 chain (bit-identical op order to the reference) runs
// thread-uniformly: a_t fetched via readlane (j uniform -> SGPR index, no
// memory in the loop; R3/R4/R5 all measured 85-108 cyc/step of scratch/LDS
// latency). Lane j CAPTURES step j's outputs via lane==j cndmask (no
// writelane — doesn't exist in this HIP frontend, R6): cv = cur value,
// pv = pre-reset integrate. Per 64-step group: one coalesced cur store and
// one __ballot(pv > THRESH) = the reference's fires > THRESHOLD bit-exactly.

#define SCAN_GROUP(RREG, GIDX)                                                \
    {                                                                         \
        float cv = 0.f, pv = 0.f;                                             \
        _Pragma("unroll 16")                                                  \
        for (int j = 0; j < 64; ++j) {                                        \
            float a = __int_as_float(                                         \
                __builtin_amdgcn_readlane(__float_as_int(RREG), j));          \
            float pre  = integ + a;              /* chain: v_add */           \
            bool  fire = pre > THRESH;           /* chain: v_cmp */           \
            float c    = fire ? dist : a;                                     \
            integ      = fire ? pre - 1.f : pre; /* chain: v_cndmask */       \
            dist       = 1.f - integ;                                         \
            bool sel   = (lane == j);                                         \
            cv = sel ? c   : cv;                                              \
            pv = sel ? pre : pv;                                              \
        }                                                                     \
        cp[(GIDX) * 64 + lane] = cv;                                          \
        unsigned long long bm = __ballot(pv > THRESH);                        \
        gmask = (lane == (GIDX)) ? bm : gmask;                                \
    }

__global__ __launch_bounds__(64) void scan_kernel(
    const float* __restrict__ alphas, float* __restrict__ cur,
    int* __restrict__ fire_times, int* __restrict__ n_fires,
    int* __restrict__ len_labels)
{
    int b    = blockIdx.x;
    int lane = threadIdx.x;                  // 0..63, one wave
    const float* ap = alphas + (size_t)b * TT;
    float*       cp = cur    + (size_t)b * TT;

    unsigned long long gmask = 0ull;         // lane g: fire mask of steps [g*64,(g+1)*64)
    float integ = 0.f, dist = 1.f;
    double dsum = 0.0;

    for (int outer = 0; outer < 4; ++outer) {
        int base = outer * 512 + lane;
        // 512 alphas -> 8 named VGPRs (coalesced dword loads, issued together)
        float r0 = ap[base +   0];
        float r1 = ap[base +  64];
        float r2 = ap[base + 128];
        float r3 = ap[base + 192];
        float r4 = ap[base + 256];
        float r5 = ap[base + 320];
        float r6 = ap[base + 384];
        float r7 = ap[base + 448];
        dsum += (double)r0 + (double)r1 + (double)r2 + (double)r3
              + (double)r4 + (double)r5 + (double)r6 + (double)r7;
        int gb = outer * 8;
        SCAN_GROUP(r0, gb + 0)
        SCAN_GROUP(r1, gb + 1)
        SCAN_GROUP(r2, gb + 2)
        SCAN_GROUP(r3, gb + 3)
        SCAN_GROUP(r4, gb + 4)
        SCAN_GROUP(r5, gb + 5)
        SCAN_GROUP(r6, gb + 6)
        SCAN_GROUP(r7, gb + 7)
    }

    // len_labels: wave double-reduce (order-insensitive; round tolerance huge)
#pragma unroll
    for (int off = 32; off; off >>= 1) dsum += __shfl_down(dsum, off, 64);
    if (lane == 0) len_labels[b] = (int)__double2int_rn(dsum);

    // Expand fire masks -> fire_times (order-preserving prefix over 32 groups;
    // lanes >= 32 hold gmask=0 and contribute nothing).
    int cnt  = __popcll(gmask);
    int pref = cnt;
#pragma unroll
    for (int off = 1; off < 64; off <<= 1) {
        int y = __shfl_up(pref, off, 64);
        if (lane >= off) pref += y;
    }
    int pos = pref - cnt;
    unsigned long long m = gmask;
    int baset = lane * 64;
    int* fp = fire_times + (size_t)b * TT;
    while (m) {
        int j = __ffsll(m) - 1;
        fp[pos++] = baset + j;
        m &= m - 1;
    }
    if (lane == 63) n_fires[b] = pref;
}

// ---------------- Kernel 3: gather segments into packed output + mask ----------------
__global__ __launch_bounds__(256) void gather_kernel(
    const float* __restrict__ hs, const float* __restrict__ alphas,
    const float* __restrict__ cur, const int* __restrict__ fire_times,
    const int* __restrict__ n_fires, const int* __restrict__ len_labels,
    float* __restrict__ out, float* __restrict__ out_mask)
{
    int ro = blockIdx.x;           // b*T + r
    int b  = ro >> 11;             // / TT
    int r  = ro & (TT - 1);
    if (threadIdx.x == 0)
        out_mask[ro] = (r < len_labels[b]) ? 1.f : 0.f;

    float4* op = (float4*)(out + (size_t)ro * DD);
    int ti = threadIdx.x;
    if (r >= n_fires[b]) {
        float4 z = {0.f, 0.f, 0.f, 0.f};
        op[ti] = z;
        return;
    }
    int t_end  = fire_times[b * TT + r];
    int t_prev = r ? fire_times[b * TT + r - 1] : -1;

    const float4* hsb = (const float4*)(hs + (size_t)b * TT * DD);
    float4 acc = {0.f, 0.f, 0.f, 0.f};
    if (t_prev >= 0) {
        float c = alphas[b * TT + t_prev] - cur[b * TT + t_prev];
        float4 h = hsb[(size_t)t_prev * 256 + ti];
        acc.x += c * h.x; acc.y += c * h.y; acc.z += c * h.z; acc.w += c * h.w;
    }
    for (int t = t_prev + 1; t <= t_end; ++t) {
        float c = cur[b * TT + t];     // broadcast load
        float4 h = hsb[(size_t)t * 256 + ti];
        acc.x += c * h.x; acc.y += c * h.y; acc.z += c * h.z; acc.w += c * h.w;
    }
    op[ti] = acc;
}

extern "C" void kernel_launch(void* const* d_in, const int* in_sizes, int n_in,
                              void* d_out, int out_size, void* d_ws, size_t ws_size,
                              hipStream_t stream) {
    const float* hs      = (const float*)d_in[0];   // [B,T,D]
    const float* hs_mask = (const float*)d_in[1];   // [B,1,T]
    const float* w       = (const float*)d_in[2];   // [D]
    const float* bias    = (const float*)d_in[3];   // scalar

    float* out      = (float*)d_out;                       // [B,T,D]
    float* out_mask = out + (size_t)BB * TT * DD;          // [B,1,T] as 0/1 floats

    float* alphas     = (float*)d_ws;                      // B*T floats
    float* cur        = alphas + BB * TT;                  // B*T floats
    int*   fire_times = (int*)(cur + BB * TT);             // B*T ints
    int*   n_fires    = fire_times + BB * TT;              // B ints
    int*   len_labels = n_fires + BB;                      // B ints

    proj_kernel<<<BB * TT / 4, 256, 0, stream>>>(hs, hs_mask, w, bias, alphas);
    scan_kernel<<<BB, 64, 0, stream>>>(alphas, cur, fire_times, n_fires, len_labels);
    gather_kernel<<<BB * TT, 256, 0, stream>>>(hs, alphas, cur, fire_times,
                                               n_fires, len_labels, out, out_mask);
}